// Round 7
// baseline (195.697 us; speedup 1.0000x reference)
//
#include <hip/hip_runtime.h>

// ---------------------------------------------------------------------------
// Gate_16501264351574: conv3x3(256ch -> 64 experts) + sigmoid + top8 + softmax
//   x: [16,256,64,64] f32, gate_w: [64,256,3,3] f32, bias: [64] f32
// out (flat f32): weights [16,8,64,64] | indices-as-f32 [16,8,64,64] | counts[64]
//
// R7 = R6 with the slot-index bug fixed: mfma_tap was called with the TAP
// index (0..8) but indexed 3-deep fragment arrays -> OOB garbage -> NaN
// scores -> all-expert-0 counts (absmax 515520). Now slot = tap % 3.
//
// Structure: barrier-free single-wave blocks + explicit software pipeline.
//  - grid 1024 x 64thr: one wave = 1 output row (64 pos) x 64 experts,
//    private LDS slab -> NO __syncthreads anywhere.
//  - A/B fragments triple-slotted (t%3), prefetched 1 tap ahead; x staging
//    for chunk q+1 split into 8 pieces issued across the tap sequence.
// ---------------------------------------------------------------------------

typedef _Float16 half8 __attribute__((ext_vector_type(8)));
typedef __attribute__((ext_vector_type(4))) float f32x4;

#define LOG2E 1.44269504f

__device__ __forceinline__ unsigned short f2h_bits(float f) {
    _Float16 h = (_Float16)f;                  // v_cvt_f16_f32, RNE
    unsigned short b;
    __builtin_memcpy(&b, &h, 2);
    return b;
}

constexpr int WB_U4 = 8 * 9 * 4 * 64;          // 18432 uint4 = 294912 B

// ---------------------------------------------------------------------------
// Prep: gate_w -> f16 B-fragments, chunk-major:
//   wB_u4[((q*9 + t)*4 + nt)*64 + lane]: e = nt*16+(lane&15), c = q*32+(lane>>4)*8+j
// ---------------------------------------------------------------------------
__global__ __launch_bounds__(256) void gate_prep(const float* __restrict__ gw,
                                                 unsigned short* __restrict__ wB) {
    int g = blockIdx.x * 256 + threadIdx.x;
    if (g >= WB_U4) return;
    int lane = g & 63;
    int nt   = (g >> 6) & 3;
    int rest = g >> 8;                          // q*9 + t
    int t = rest % 9, q = rest / 9;
    int e  = nt * 16 + (lane & 15);
    int c0 = q * 32 + (lane >> 4) * 8;
    unsigned short o[8];
#pragma unroll
    for (int j = 0; j < 8; ++j)
        o[j] = f2h_bits(gw[(e * 256 + c0 + j) * 9 + t]);
    uint4 pk;
    pk.x = (unsigned)o[0] | ((unsigned)o[1] << 16);
    pk.y = (unsigned)o[2] | ((unsigned)o[3] << 16);
    pk.z = (unsigned)o[4] | ((unsigned)o[5] << 16);
    pk.w = (unsigned)o[6] | ((unsigned)o[7] << 16);
    ((uint4*)wB)[g] = pk;
}

// ---------------------------------------------------------------------------
// Main. Grid 1024 x 64 threads (ONE wave per block, no barriers at all).
// blk: b = blk&15 (image -> XCD locality), r = blk>>4 (output row).
// LDS: xs double slab [2][3 rows][66 w'][40 c] f16 (31680B) + bias + hist.
// ---------------------------------------------------------------------------
constexpr int CSTR = 40;                       // shorts per (row,w') site (16B-aligned)
constexpr int SLAB = 3 * 66 * CSTR;            // 7920 shorts = 15840 B
constexpr int SSTR = 68;                       // fp32 score row stride (272B, 16B-aligned)

__global__ __launch_bounds__(64, 2) void gate_main(
    const float* __restrict__ x, const float* __restrict__ bias,
    const unsigned short* __restrict__ wB, float* __restrict__ out) {
    __shared__ unsigned short xs[2 * SLAB];    // 31680 B; scf aliases (17408 B)
    __shared__ float bias_s[64];
    __shared__ int   hist[64];

    const int lane = threadIdx.x;              // 0..63
    const int blk  = blockIdx.x;
    const int b    = blk & 15;
    const int r    = blk >> 4;                 // output row 0..63

    bias_s[lane] = bias[lane];
    hist[lane]   = 0;

    // ---------------- staging helpers (chunk -> slab, 8 pieces) ------------
    // sites s = 0..197 map to (row = s/66, w' = s%66); lane covers s = lane,
    // lane+64, lane+128, lane+192(<198). piece p: si = p>>1, chHalf = p&1.
    auto issue = [&](int qn, int p, float* tb) {
        const int si = p >> 1, chh = p & 1;
        const int s  = lane + si * 64;
        if (s < 198) {
            const int row = s / 66, wp = s - row * 66;
            const int gr = r - 1 + row, gw = wp - 1;
            if (gr >= 0 && gr < 64 && gw >= 0 && gw < 64) {
                const float* p0 =
                    x + (((size_t)(b * 256 + qn * 32 + chh * 16) * 64 + gr) * 64 + gw);
#pragma unroll
                for (int u = 0; u < 16; ++u) tb[u] = p0[(size_t)u * 4096];
            } else {
#pragma unroll
                for (int u = 0; u < 16; ++u) tb[u] = 0.f;
            }
        }
    };
    auto commit = [&](int p, const float* tb, unsigned short* dst) {
        const int si = p >> 1, chh = p & 1;
        const int s  = lane + si * 64;
        if (s < 198) {
            const int row = s / 66, wp = s - row * 66;
            unsigned short* d = dst + (row * 66 + wp) * CSTR + chh * 16;
#pragma unroll
            for (int h8 = 0; h8 < 2; ++h8) {
                uint4 pk;
                pk.x = (unsigned)f2h_bits(tb[h8*8+0]) | ((unsigned)f2h_bits(tb[h8*8+1]) << 16);
                pk.y = (unsigned)f2h_bits(tb[h8*8+2]) | ((unsigned)f2h_bits(tb[h8*8+3]) << 16);
                pk.z = (unsigned)f2h_bits(tb[h8*8+4]) | ((unsigned)f2h_bits(tb[h8*8+5]) << 16);
                pk.w = (unsigned)f2h_bits(tb[h8*8+6]) | ((unsigned)f2h_bits(tb[h8*8+7]) << 16);
                *(uint4*)(d + h8 * 8) = pk;
            }
        }
    };

    // ---------------- fragment slots (3-deep, distance-1 prefetch) ---------
    half8 Aa[3][4];
    uint4 Bb[3][4];
    auto prefA = [&](const unsigned short* buf, int t, int slot) {
        const int kh = t / 3, kw = t % 3;
#pragma unroll
        for (int mt = 0; mt < 4; ++mt)
            Aa[slot][mt] = *(const half8*)(
                buf + (kh * 66 + mt * 16 + (lane & 15) + kw) * CSTR + (lane >> 4) * 8);
    };
    auto prefB = [&](int q_, int t_, int slot) {
        const uint4* bp = (const uint4*)wB + ((q_ * 9 + t_) * 4) * 64 + lane;
#pragma unroll
        for (int nt = 0; nt < 4; ++nt) Bb[slot][nt] = bp[nt * 64];
    };

    f32x4 acc[4][4];
#pragma unroll
    for (int mt = 0; mt < 4; ++mt)
#pragma unroll
        for (int nt = 0; nt < 4; ++nt) acc[mt][nt] = (f32x4){0.f, 0.f, 0.f, 0.f};

    // NOTE: takes the TAP index, computes the slot (R6 bug: indexed by tap).
    auto mfma_tap = [&](int t) {
        const int slot = t % 3;
#pragma unroll
        for (int nt = 0; nt < 4; ++nt) {
            half8 bfr;
            __builtin_memcpy(&bfr, &Bb[slot][nt], 16);
#pragma unroll
            for (int mt = 0; mt < 4; ++mt)
                acc[mt][nt] = __builtin_amdgcn_mfma_f32_16x16x32_f16(
                    Aa[slot][mt], bfr, acc[mt][nt], 0, 0, 0);
        }
    };

    float t0b[16], t1b[16];

    // ---------------- prologue: stage chunk 0, preload tap-0 frags ---------
    issue(0, 0, t0b); issue(0, 1, t1b);
    commit(0, t0b, xs); issue(0, 2, t0b);
    commit(1, t1b, xs); issue(0, 3, t1b);
    commit(2, t0b, xs); issue(0, 4, t0b);
    commit(3, t1b, xs); issue(0, 5, t1b);
    commit(4, t0b, xs); issue(0, 6, t0b);
    commit(5, t1b, xs); issue(0, 7, t1b);
    commit(6, t0b, xs);
    commit(7, t1b, xs);
    prefA(xs, 0, 0);
    prefB(0, 0, 0);

    // ---------------- K loop: 8 chunks x 9 taps, barrier-free --------------
#pragma unroll 1
    for (int q = 0; q < 8; ++q) {
        const unsigned short* cur = xs + (q & 1) * SLAB;
        unsigned short*       nxt = xs + ((q + 1) & 1) * SLAB;
        if (q < 7) {
            issue(q + 1, 0, t0b); issue(q + 1, 1, t1b);
            prefA(cur, 1, 1); prefB(q, 1, 1); mfma_tap(0);
            prefA(cur, 2, 2); prefB(q, 2, 2); mfma_tap(1);
            commit(0, t0b, nxt); issue(q + 1, 2, t0b);
            prefA(cur, 3, 0); prefB(q, 3, 0); mfma_tap(2);
            commit(1, t1b, nxt); issue(q + 1, 3, t1b);
            prefA(cur, 4, 1); prefB(q, 4, 1); mfma_tap(3);
            commit(2, t0b, nxt); issue(q + 1, 4, t0b);
            prefA(cur, 5, 2); prefB(q, 5, 2); mfma_tap(4);
            commit(3, t1b, nxt); issue(q + 1, 5, t1b);
            prefA(cur, 6, 0); prefB(q, 6, 0); mfma_tap(5);
            commit(4, t0b, nxt); issue(q + 1, 6, t0b);
            prefA(cur, 7, 1); prefB(q, 7, 1); mfma_tap(6);
            commit(5, t1b, nxt); issue(q + 1, 7, t1b);
            prefA(cur, 8, 2); prefB(q, 8, 2); mfma_tap(7);
            commit(6, t0b, nxt);
            commit(7, t1b, nxt);
            prefA(nxt, 0, 0); prefB(q + 1, 0, 0);   // next-chunk tap 0
            mfma_tap(8);
        } else {
            prefA(cur, 1, 1); prefB(q, 1, 1); mfma_tap(0);
            prefA(cur, 2, 2); prefB(q, 2, 2); mfma_tap(1);
            prefA(cur, 3, 0); prefB(q, 3, 0); mfma_tap(2);
            prefA(cur, 4, 1); prefB(q, 4, 1); mfma_tap(3);
            prefA(cur, 5, 2); prefB(q, 5, 2); mfma_tap(4);
            prefA(cur, 6, 0); prefB(q, 6, 0); mfma_tap(5);
            prefA(cur, 7, 1); prefB(q, 7, 1); mfma_tap(6);
            prefA(cur, 8, 2); prefB(q, 8, 2); mfma_tap(7);
            mfma_tap(8);
        }
    }

    // ---------------- epilogue (all same-wave, still barrier-free) ---------
    float* scf = (float*)xs;                   // [64][68] f32, aliases slab
#pragma unroll
    for (int mt = 0; mt < 4; ++mt)
#pragma unroll
        for (int nt = 0; nt < 4; ++nt)
#pragma unroll
            for (int rr = 0; rr < 4; ++rr) {
                float v = acc[mt][nt][rr];
                float s = 1.f / (1.f + __builtin_amdgcn_exp2f(-v * LOG2E));
                int p = mt * 16 + ((lane >> 4) << 2) + rr;
                int e = nt * 16 + (lane & 15);
                scf[p * SSTR + e] = s;
            }

    // top-8 of 64 for position p = lane; jax tie-break (lower index first)
    const float* row = scf + lane * SSTR;
    float tv[8];
    int   ti[8];
#pragma unroll
    for (int k = 0; k < 8; ++k) { tv[k] = -3.0e38f; ti[k] = 0; }
#pragma unroll
    for (int j4 = 0; j4 < 16; ++j4) {
        f32x4 blkv = *(const f32x4*)(row + j4 * 4);
#pragma unroll
        for (int j = 0; j < 4; ++j) {
            int   e  = j4 * 4 + j;
            float bs = blkv[j] + bias_s[e];
            if (bs > tv[7]) {
                tv[7] = bs; ti[7] = e;
#pragma unroll
                for (int k = 7; k > 0; --k) {
                    float fa = tv[k - 1], fb = tv[k];
                    int   ia = ti[k - 1], ib = ti[k];
                    bool  sw = fb > fa;
                    tv[k - 1] = sw ? fb : fa; tv[k] = sw ? fa : fb;
                    ti[k - 1] = sw ? ib : ia; ti[k] = sw ? ia : ib;
                }
            }
        }
    }
    // softmax over UNbiased scores of the selected 8
    float u[8], mx = -3.0e38f;
#pragma unroll
    for (int k = 0; k < 8; ++k) { u[k] = tv[k] - bias_s[ti[k]]; mx = fmaxf(mx, u[k]); }
    float ex[8], sum = 0.f;
#pragma unroll
    for (int k = 0; k < 8; ++k) { ex[k] = __builtin_amdgcn_exp2f((u[k] - mx) * LOG2E); sum += ex[k]; }
    float inv = 1.f / sum;

    const int obase = b * 32768 + r * 64 + lane;   // [b][k][h=r][w=lane]
#pragma unroll
    for (int k = 0; k < 8; ++k) {
        out[obase + k * 4096]          = ex[k] * inv;     // weights
        out[524288 + obase + k * 4096] = (float)ti[k];    // indices (as f32)
        atomicAdd(&hist[ti[k]], 1);                       // LDS, same wave
    }
    atomicAdd(out + 1048576 + lane, (float)hist[lane]);   // counts (as f32)
}

// ---------------------------------------------------------------------------
extern "C" void kernel_launch(void* const* d_in, const int* in_sizes, int n_in,
                              void* d_out, int out_size, void* d_ws, size_t ws_size,
                              hipStream_t stream) {
    const float* x    = (const float*)d_in[0];
    const float* gw   = (const float*)d_in[1];
    const float* bias = (const float*)d_in[2];
    float* out = (float*)d_out;
    unsigned short* wB = (unsigned short*)d_ws;   // 294912 B

    hipMemsetAsync((char*)d_out + (size_t)1048576 * sizeof(float), 0,
                   64 * sizeof(float), stream);   // counts accumulate from 0
    gate_prep<<<72, 256, 0, stream>>>(gw, wB);
    gate_main<<<1024, 64, 0, stream>>>(x, bias, wB, out);
}

// Round 8
// 153.270 us; speedup vs baseline: 1.2768x; 1.2768x over previous
//
#include <hip/hip_runtime.h>

// ---------------------------------------------------------------------------
// Gate_16501264351574: conv3x3(256ch -> 64 experts) + sigmoid + top8 + softmax
//   x: [16,256,64,64] f32, gate_w: [64,256,3,3] f32, bias: [64] f32
// out (flat f32): weights [16,8,64,64] | indices-as-f32 [16,8,64,64] | counts[64]
//
// R8: small-tile pipelined waves. R7's 64x64/wave tile needed ~190 VGPRs ->
// 67MB spill writeback. Now: block (256thr) = 1 output row; wave = 32pos x
// 32exp (acc=16). A/B frags 3-slot rotated, distance-1 prefetch; x staged as
// 4 precomputed per-thread tasks. ~110 VGPRs -> 4 blocks/CU = 4 waves/SIMD.
// One barrier/chunk; cross-block overlap hides drains.
// ---------------------------------------------------------------------------

typedef _Float16 half8 __attribute__((ext_vector_type(8)));
typedef __attribute__((ext_vector_type(4))) float f32x4;

#define LOG2E 1.44269504f

__device__ __forceinline__ unsigned short f2h_bits(float f) {
    _Float16 h = (_Float16)f;                  // v_cvt_f16_f32, RNE
    unsigned short b;
    __builtin_memcpy(&b, &h, 2);
    return b;
}

constexpr int WB_U4 = 8 * 9 * 4 * 64;          // 18432 uint4 = 294912 B

// ---------------------------------------------------------------------------
// Prep: gate_w -> f16 B-fragments, chunk-major:
//   wB_u4[((q*9 + t)*4 + nt)*64 + lane]: e = nt*16+(lane&15), c = q*32+(lane>>4)*8+j
// Also zeroes the counts region of out (replaces a memset dispatch).
// ---------------------------------------------------------------------------
__global__ __launch_bounds__(256) void gate_prep(const float* __restrict__ gw,
                                                 unsigned short* __restrict__ wB,
                                                 float* __restrict__ out) {
    int g = blockIdx.x * 256 + threadIdx.x;
    if (blockIdx.x == 0 && threadIdx.x < 64) out[1048576 + threadIdx.x] = 0.f;
    if (g >= WB_U4) return;
    int lane = g & 63;
    int nt   = (g >> 6) & 3;
    int rest = g >> 8;                          // q*9 + t
    int t = rest % 9, q = rest / 9;
    int e  = nt * 16 + (lane & 15);
    int c0 = q * 32 + (lane >> 4) * 8;
    unsigned short o[8];
#pragma unroll
    for (int j = 0; j < 8; ++j)
        o[j] = f2h_bits(gw[(e * 256 + c0 + j) * 9 + t]);
    uint4 pk;
    pk.x = (unsigned)o[0] | ((unsigned)o[1] << 16);
    pk.y = (unsigned)o[2] | ((unsigned)o[3] << 16);
    pk.z = (unsigned)o[4] | ((unsigned)o[5] << 16);
    pk.w = (unsigned)o[6] | ((unsigned)o[7] << 16);
    ((uint4*)wB)[g] = pk;
}

// ---------------------------------------------------------------------------
// Main. Grid 1024 x 256 thr: b = blk&15 (image -> XCD), r = blk>>4 (row).
// Wave rw: ph = rw>>1 (pos half), eh = rw&1 (expert half); tile 32x32.
// LDS: xs double slab [2][3 rows][66 w'][40 c] f16 = 31680 B (+bias+hist);
// epilogue scf [64][68] f32 (17408 B) aliases xs.
// ---------------------------------------------------------------------------
constexpr int CSTR = 40;                       // shorts per (row,w') site
constexpr int SLAB = 3 * 66 * CSTR;            // 7920 shorts = 15840 B
constexpr int SSTR = 68;                       // fp32 score row stride

__global__ __launch_bounds__(256, 4) void gate_main(
    const float* __restrict__ x, const float* __restrict__ bias,
    const unsigned short* __restrict__ wB, float* __restrict__ out) {
    __shared__ unsigned short xs[2 * SLAB];    // 31680 B
    __shared__ float bias_s[64];
    __shared__ int   hist[64];

    const int tid  = threadIdx.x;
    const int lane = tid & 63;
    const int rw   = tid >> 6;
    const int blk  = blockIdx.x;
    const int b    = blk & 15;
    const int r    = blk >> 4;                 // output row 0..63

    if (tid < 64) { bias_s[tid] = bias[tid]; hist[tid] = 0; }

    // ---- staging task descriptors (4 tasks/thread, precomputed) ----------
    // Task T = tid + i*256, T < 792 = 198 sites x 4 channel-groups(8ch).
    // T -> chh = T/198 (8-ch group), s = T%198 -> row=s/66, w'=s%66.
    bool tEx[4], tOk[4];
    int  tSrc[4], tDst[4];
#pragma unroll
    for (int i = 0; i < 4; ++i) {
        int T = tid + i * 256;
        tEx[i] = (T < 792);
        int chh = T / 198, s = T - chh * 198;
        int row2 = s / 66, wp = s - row2 * 66;
        int gr = r - 1 + row2, gwc = wp - 1;
        tOk[i]  = tEx[i] && (gr >= 0) && (gr < 64) && (gwc >= 0) && (gwc < 64);
        tSrc[i] = ((b * 256 + chh * 8) * 64 + gr) * 64 + gwc;   // + q*131072
        tDst[i] = (row2 * 66 + wp) * CSTR + chh * 8;            // shorts
    }

    float tb0[8], tb1[8];
    auto issue = [&](int i, int q, float* tb) {
        if (tOk[i]) {
            const float* p = x + tSrc[i] + q * 131072;
#pragma unroll
            for (int u = 0; u < 8; ++u) tb[u] = p[u * 4096];
        } else {
#pragma unroll
            for (int u = 0; u < 8; ++u) tb[u] = 0.f;
        }
    };
    auto commit = [&](int i, const float* tb, unsigned short* dst) {
        if (tEx[i]) {
            uint4 pk;
            pk.x = (unsigned)f2h_bits(tb[0]) | ((unsigned)f2h_bits(tb[1]) << 16);
            pk.y = (unsigned)f2h_bits(tb[2]) | ((unsigned)f2h_bits(tb[3]) << 16);
            pk.z = (unsigned)f2h_bits(tb[4]) | ((unsigned)f2h_bits(tb[5]) << 16);
            pk.w = (unsigned)f2h_bits(tb[6]) | ((unsigned)f2h_bits(tb[7]) << 16);
            *(uint4*)(dst + tDst[i]) = pk;
        }
    };

    // ---- fragment slots (3-deep rotation, statically indexed) -------------
    const int ph = rw >> 1, eh = rw & 1;
    half8 Aa[3][2];
    uint4 Bb[3][2];
    auto prefA = [&](const unsigned short* buf, int t, int slot) {
        const int kh = t / 3, kw = t % 3;
        const unsigned short* abase =
            buf + (kh * 66 + ph * 32 + (lane & 15) + kw) * CSTR + (lane >> 4) * 8;
#pragma unroll
        for (int mt = 0; mt < 2; ++mt)
            Aa[slot][mt] = *(const half8*)(abase + mt * 16 * CSTR);
    };
    auto prefB = [&](int q, int t, int slot) {
        const uint4* bp = (const uint4*)wB + ((q * 9 + t) * 4 + eh * 2) * 64 + lane;
#pragma unroll
        for (int nt = 0; nt < 2; ++nt) Bb[slot][nt] = bp[nt * 64];
    };

    f32x4 acc[2][2];
#pragma unroll
    for (int mt = 0; mt < 2; ++mt)
#pragma unroll
        for (int nt = 0; nt < 2; ++nt) acc[mt][nt] = (f32x4){0.f, 0.f, 0.f, 0.f};

    auto mfma_tap = [&](int slot) {            // slot, not tap (R6 lesson)
#pragma unroll
        for (int nt = 0; nt < 2; ++nt) {
            half8 bfr;
            __builtin_memcpy(&bfr, &Bb[slot][nt], 16);
#pragma unroll
            for (int mt = 0; mt < 2; ++mt)
                acc[mt][nt] = __builtin_amdgcn_mfma_f32_16x16x32_f16(
                    Aa[slot][mt], bfr, acc[mt][nt], 0, 0, 0);
        }
    };

    // ---- prologue: stage chunk 0 ------------------------------------------
    issue(0, 0, tb0); issue(1, 0, tb1);
    commit(0, tb0, xs); commit(1, tb1, xs);
    issue(2, 0, tb0); issue(3, 0, tb1);
    commit(2, tb0, xs); commit(3, tb1, xs);
    __syncthreads();

    // ---- K loop: 8 chunks x 9 taps, 1 barrier per chunk -------------------
#pragma unroll 1
    for (int q = 0; q < 8; ++q) {
        const unsigned short* cur = xs + (q & 1) * SLAB;
        unsigned short*       nxt = xs + ((q + 1) & 1) * SLAB;
        const bool st = (q < 7);
        if (st) { issue(0, q + 1, tb0); issue(1, q + 1, tb1); }
        prefA(cur, 0, 0); prefB(q, 0, 0);
        prefA(cur, 1, 1); prefB(q, 1, 1); mfma_tap(0);
        prefA(cur, 2, 2); prefB(q, 2, 2); mfma_tap(1);
        prefA(cur, 3, 0); prefB(q, 3, 0); mfma_tap(2);
        prefA(cur, 4, 1); prefB(q, 4, 1); mfma_tap(0);   // slot(3)=0 consumed
        if (st) {
            commit(0, tb0, nxt); commit(1, tb1, nxt);
            issue(2, q + 1, tb0); issue(3, q + 1, tb1);
        }
        prefA(cur, 5, 2); prefB(q, 5, 2); mfma_tap(1);   // slot(4)=1
        prefA(cur, 6, 0); prefB(q, 6, 0); mfma_tap(2);   // slot(5)=2
        prefA(cur, 7, 1); prefB(q, 7, 1); mfma_tap(0);   // slot(6)=0
        prefA(cur, 8, 2); prefB(q, 8, 2); mfma_tap(1);   // slot(7)=1
        mfma_tap(2);                                     // slot(8)=2
        if (st) { commit(2, tb0, nxt); commit(3, tb1, nxt); }
        __syncthreads();
    }

    // ---- epilogue: sigmoid -> fp32 scores in LDS (aliases xs) -------------
    float* scf = (float*)xs;                   // [64][68] f32 = 17408 B
#pragma unroll
    for (int mt = 0; mt < 2; ++mt)
#pragma unroll
        for (int nt = 0; nt < 2; ++nt)
#pragma unroll
            for (int rr = 0; rr < 4; ++rr) {
                float v = acc[mt][nt][rr];
                float s = 1.f / (1.f + __builtin_amdgcn_exp2f(-v * LOG2E));
                int p = ph * 32 + mt * 16 + ((lane >> 4) << 2) + rr;
                int e = eh * 32 + nt * 16 + (lane & 15);
                scf[p * SSTR + e] = s;
            }
    __syncthreads();

    if (tid < 64) {
        // top-8 of 64; jax tie-break (lower idx first): ascending scan + strict >
        const float* row = scf + tid * SSTR;
        float tv[8];
        int   ti[8];
#pragma unroll
        for (int k = 0; k < 8; ++k) { tv[k] = -3.0e38f; ti[k] = 0; }
#pragma unroll
        for (int j4 = 0; j4 < 16; ++j4) {
            f32x4 blkv = *(const f32x4*)(row + j4 * 4);
#pragma unroll
            for (int j = 0; j < 4; ++j) {
                int   e  = j4 * 4 + j;
                float bs = blkv[j] + bias_s[e];
                if (bs > tv[7]) {
                    tv[7] = bs; ti[7] = e;
#pragma unroll
                    for (int k = 7; k > 0; --k) {
                        float fa = tv[k - 1], fb = tv[k];
                        int   ia = ti[k - 1], ib = ti[k];
                        bool  sw = fb > fa;
                        tv[k - 1] = sw ? fb : fa; tv[k] = sw ? fa : fb;
                        ti[k - 1] = sw ? ib : ia; ti[k] = sw ? ia : ib;
                    }
                }
            }
        }
        // softmax over UNbiased scores of the selected 8
        float u[8], mx = -3.0e38f;
#pragma unroll
        for (int k = 0; k < 8; ++k) { u[k] = tv[k] - bias_s[ti[k]]; mx = fmaxf(mx, u[k]); }
        float ex[8], sum = 0.f;
#pragma unroll
        for (int k = 0; k < 8; ++k) { ex[k] = __builtin_amdgcn_exp2f((u[k] - mx) * LOG2E); sum += ex[k]; }
        float inv = 1.f / sum;

        int obase = b * 32768 + r * 64 + tid;  // [b][k][h=r][w=tid]
#pragma unroll
        for (int k = 0; k < 8; ++k) {
            out[obase + k * 4096]          = ex[k] * inv;     // weights
            out[524288 + obase + k * 4096] = (float)ti[k];    // indices (as f32)
            atomicAdd(&hist[ti[k]], 1);
        }
    }
    __syncthreads();
    if (tid < 64) atomicAdd(out + 1048576 + tid, (float)hist[tid]);  // counts
}

// ---------------------------------------------------------------------------
extern "C" void kernel_launch(void* const* d_in, const int* in_sizes, int n_in,
                              void* d_out, int out_size, void* d_ws, size_t ws_size,
                              hipStream_t stream) {
    const float* x    = (const float*)d_in[0];
    const float* gw   = (const float*)d_in[1];
    const float* bias = (const float*)d_in[2];
    float* out = (float*)d_out;
    unsigned short* wB = (unsigned short*)d_ws;   // 294912 B

    gate_prep<<<72, 256, 0, stream>>>(gw, wB, out);   // also zeroes counts
    gate_main<<<1024, 256, 0, stream>>>(x, bias, wB, out);
}